// Round 7
// baseline (233.235 us; speedup 1.0000x reference)
//
#include <hip/hip_runtime.h>
#include <stdint.h>

#define TTOK 1024
#define DMODEL 1024
#define NEXP 16
#define TOPK 4
#define INTER 512
#define NSHI 1024
#define RSCALE 2.5f

typedef __bf16 bf16;
typedef __bf16 bf16x8 __attribute__((ext_vector_type(8)));
typedef __bf16 bf16x4 __attribute__((ext_vector_type(4)));
typedef float f32x4 __attribute__((ext_vector_type(4)));

// LDS plane stride: 128 rows * 16B + 16 pad
#define PLANE 2064

// bf16 weight buffer layout (element offsets)
#define OFF_GP 0L
#define OFF_UP 8388608L   // 16*512*1024
#define OFF_DP 16777216L
#define OFF_SG 25165824L
#define OFF_SU 26214400L
#define OFF_SD 27262976L
#define WTOT   28311552L  // total bf16 elems

// Raw barrier: lgkmcnt(0) for cross-wave LDS safety, no vmcnt drain.
#define LGKM_BAR()                                            \
  do {                                                        \
    asm volatile("s_waitcnt lgkmcnt(0)" ::: "memory");        \
    __builtin_amdgcn_s_barrier();                             \
  } while (0)

// ---------------- weights fp32 -> bf16 v3: 2 float8 units/thread, all 4 loads
// issued before stores (named regs -> compiler cannot serialize); 16B stores.
__global__ __launch_bounds__(256)
void convert_kernel(const float* __restrict__ s0, const float* __restrict__ s1,
                    const float* __restrict__ s2, const float* __restrict__ s3,
                    const float* __restrict__ s4, const float* __restrict__ s5,
                    bf16* __restrict__ dst) {
  const long j0 = (long)blockIdx.x * 512 + threadIdx.x;  // float8 unit
  const long j1 = j0 + 256;
  const float *srcA, *srcB;
  long la, lb;
  if (j0 < 1048576L)      { srcA = s0; la = j0; }
  else if (j0 < 2097152L) { srcA = s1; la = j0 - 1048576L; }
  else if (j0 < 3145728L) { srcA = s2; la = j0 - 2097152L; }
  else if (j0 < 3276800L) { srcA = s3; la = j0 - 3145728L; }
  else if (j0 < 3407872L) { srcA = s4; la = j0 - 3276800L; }
  else                    { srcA = s5; la = j0 - 3407872L; }
  if (j1 < 1048576L)      { srcB = s0; lb = j1; }
  else if (j1 < 2097152L) { srcB = s1; lb = j1 - 1048576L; }
  else if (j1 < 3145728L) { srcB = s2; lb = j1 - 2097152L; }
  else if (j1 < 3276800L) { srcB = s3; lb = j1 - 3145728L; }
  else if (j1 < 3407872L) { srcB = s4; lb = j1 - 3276800L; }
  else                    { srcB = s5; lb = j1 - 3407872L; }
  // issue all four loads before any store
  const float4 a0 = ((const float4*)srcA)[la * 2];
  const float4 a1 = ((const float4*)srcA)[la * 2 + 1];
  const float4 b0 = ((const float4*)srcB)[lb * 2];
  const float4 b1 = ((const float4*)srcB)[lb * 2 + 1];
  bf16x8 oa, ob;
  oa[0] = (bf16)a0.x; oa[1] = (bf16)a0.y; oa[2] = (bf16)a0.z; oa[3] = (bf16)a0.w;
  oa[4] = (bf16)a1.x; oa[5] = (bf16)a1.y; oa[6] = (bf16)a1.z; oa[7] = (bf16)a1.w;
  ob[0] = (bf16)b0.x; ob[1] = (bf16)b0.y; ob[2] = (bf16)b0.z; ob[3] = (bf16)b0.w;
  ob[4] = (bf16)b1.x; ob[5] = (bf16)b1.y; ob[6] = (bf16)b1.z; ob[7] = (bf16)b1.w;
  ((bf16x8*)dst)[j0] = oa;
  ((bf16x8*)dst)[j1] = ob;
}

// ---------------- scores (+ fused x->bf16): logits = x @ gw^T, fp32 exact ----------------
__global__ __launch_bounds__(256)
void scores_kernel(const float* __restrict__ x, const float* __restrict__ gw,
                   float* __restrict__ scores, bf16* __restrict__ xbf) {
  __shared__ float gws[16 * 1024];
  const int tid = threadIdx.x;
  const float4* gw4 = (const float4*)gw;
#pragma unroll
  for (int i0 = 0; i0 < 4096; i0 += 256) {
    const int i = i0 + tid;
    const int e = i >> 8;
    const int dq = (i & 255) << 2;
    const int dd = (dq + 4 * e) & 1023;
    ((float4*)gws)[(e << 8) + (dd >> 2)] = gw4[i];
  }
  // fused x -> bf16 (4 tokens/block, 1024 float4)
  {
    const long xb = (long)blockIdx.x * 1024;
#pragma unroll
    for (int p = 0; p < 4; ++p) {
      const long j = xb + p * 256 + tid;
      const float4 v = ((const float4*)x)[j];
      bf16x4 o;
      o.x = (bf16)v.x; o.y = (bf16)v.y; o.z = (bf16)v.z; o.w = (bf16)v.w;
      ((bf16x4*)xbf)[j] = o;
    }
  }
  __syncthreads();
  const int kq = tid >> 6;
  const int lane = tid & 63;
  const int tl = lane >> 4;
  const int e = lane & 15;
  const long token = (long)blockIdx.x * 4 + tl;
  float acc = 0.f;
  const int dbase = kq * 256;
#pragma unroll 8
  for (int i = 0; i < 256; i += 4) {
    const int d = dbase + i;
    const float4 xv = *(const float4*)&x[token * DMODEL + d];
    const float4 wv = *(const float4*)&gws[(e << 10) + ((d + 4 * e) & 1023)];
    acc += xv.x * wv.x + xv.y * wv.y + xv.z * wv.z + xv.w * wv.w;
  }
  __syncthreads();
  gws[kq * 64 + lane] = acc;
  __syncthreads();
  if (kq == 0) {
    const float s = gws[lane] + gws[64 + lane] + gws[128 + lane] + gws[192 + lane];
    scores[token * 16 + e] = s;
  }
}

// ---------------- route: top-k + plan + fill, fused single-block ----------------
__global__ __launch_bounds__(1024)
void route_kernel(const float* __restrict__ scores, const float* __restrict__ gb,
                  float* __restrict__ tokW, int* __restrict__ slotTok,
                  int* __restrict__ tokSlot, int* __restrict__ offs,
                  int* __restrict__ tileE, int* __restrict__ tileR,
                  int* __restrict__ tileCnt) {
  __shared__ int cnt[NEXP], cur[NEXP];
  const int t = threadIdx.x;
  if (t < NEXP) cnt[t] = 0;
  __syncthreads();
  float sc[NEXP], s[NEXP];
#pragma unroll
  for (int e = 0; e < NEXP; ++e) {
    const float l = scores[t * NEXP + e];
    sc[e] = 1.f / (1.f + expf(-l));
    s[e] = sc[e] + gb[e];
  }
  float gsc[4];
#pragma unroll
  for (int g = 0; g < 4; ++g) {
    const float a = s[4 * g], b = s[4 * g + 1], c = s[4 * g + 2], d = s[4 * g + 3];
    gsc[g] = fmaxf(fmaxf(fmaxf(a + b, a + c), fmaxf(a + d, b + c)),
                   fmaxf(b + d, c + d));
  }
  int g0 = 0;
  for (int g = 1; g < 4; ++g) if (gsc[g] > gsc[g0]) g0 = g;
  int g1 = (g0 == 0) ? 1 : 0;
  for (int g = 0; g < 4; ++g) if (g != g0 && gsc[g] > gsc[g1]) g1 = g;
  float m[NEXP];
#pragma unroll
  for (int e = 0; e < NEXP; ++e) {
    const int g = e >> 2;
    m[e] = (g == g0 || g == g1) ? s[e] : -1.f;
  }
  int idx[TOPK]; float wv[TOPK]; float wsum = 0.f;
  for (int k = 0; k < TOPK; ++k) {
    int am = 0; float best = m[0];
    for (int e2 = 1; e2 < NEXP; ++e2)
      if (m[e2] > best) { best = m[e2]; am = e2; }
    idx[k] = am; wv[k] = sc[am]; wsum += sc[am]; m[am] = -2.f;
  }
#pragma unroll
  for (int k = 0; k < TOPK; ++k) atomicAdd(&cnt[idx[k]], 1);
  __syncthreads();
  if (t == 0) {
    int acc = 0;
#pragma unroll
    for (int e = 0; e < NEXP; ++e) {
      offs[e] = acc; cur[e] = acc; acc += cnt[e];
    }
    offs[NEXP] = acc;
    int tc = 0;
    int roff = 0;
    for (int e = 0; e < NEXP; ++e) {
      const int end = roff + cnt[e];
      for (int r = roff; r < end; r += 128) { tileE[tc] = e; tileR[tc] = r; ++tc; }
      roff = end;
    }
    for (int r = 0; r < TTOK; r += 128) { tileE[tc] = NEXP; tileR[tc] = r; ++tc; }
    tileCnt[0] = tc;  // <= 47 + 8 = 55
  }
  __syncthreads();
  const float scl = RSCALE / wsum;
#pragma unroll
  for (int k = 0; k < TOPK; ++k) {
    const int slot = atomicAdd(&cur[idx[k]], 1);
    slotTok[slot] = t;
    tokSlot[t * TOPK + k] = slot;
    tokW[t * TOPK + k] = wv[k] * scl;
  }
}

// ---------------- gate+up grouped GEMM (128M x 128N, BK=64), bf16 weights, fused SwiGLU ----
// N-tile 64->128: 64 MFMA per k-step per wave vs 24 ds_read_b128 — attacks the
// barrier/staging-per-FLOP limit now that weights are L3-resident.
__global__ __launch_bounds__(256, 2)
void gateup_gemm(const bf16* __restrict__ xbf, const int* __restrict__ slotTok,
                 const int* __restrict__ offs, const int* __restrict__ tileE,
                 const int* __restrict__ tileR, const int* __restrict__ tileCnt,
                 const bf16* __restrict__ wbf,
                 bf16* __restrict__ interR, bf16* __restrict__ interS) {
  const int y = blockIdx.y;
  if (y >= tileCnt[0]) return;
  const int e = tileE[y];
  const bool shd = (e == NEXP);
  const int n0 = blockIdx.x * 128;
  if (!shd && n0 >= INTER) return;  // routed uses grid.x 0..3
  const int rowStart = tileR[y];
  const int rowEnd = shd ? rowStart + 128 : offs[e + 1];
  const bf16* wgp = shd ? wbf + OFF_SG : wbf + OFF_GP + (long)e * INTER * DMODEL;
  const bf16* wup = shd ? wbf + OFF_SU : wbf + OFF_UP + (long)e * INTER * DMODEL;

  __shared__ __attribute__((aligned(16))) char As[8 * PLANE];
  __shared__ __attribute__((aligned(16))) char Bg[8 * PLANE];
  __shared__ __attribute__((aligned(16))) char Bu[8 * PLANE];
  __shared__ int tokS[128];

  const int tid = threadIdx.x;
  if (tid < 128) {
    const int r = rowStart + tid;
    tokS[tid] = shd ? r : slotTok[r < rowEnd ? r : rowStart];
  }
  __syncthreads();

  // A staging: round p: row = p*32 + (tid>>3), oct = tid&7
  const int arw = tid >> 3;
  const int aoct = tid & 7;
  const bf16* aSrc[4];
#pragma unroll
  for (int p = 0; p < 4; ++p)
    aSrc[p] = xbf + (long)tokS[p * 32 + arw] * DMODEL + aoct * 8;

  // B staging: 128 threads per matrix; 128 N-rows: round p: row = p*16 + (u>>3), oct = u&7
  const int bu_ = tid >> 7;
  const int u = tid & 127;
  const int brw = u >> 3;   // 0..15
  const int boct = u & 7;
  const bf16* bSrc = (bu_ ? wup : wgp) + (long)(n0 + brw) * DMODEL + boct * 8;
  char* bDst = bu_ ? Bu : Bg;

  const int lane = tid & 63;
  const int wv = tid >> 6;
  const int q = lane >> 4;
  const int l15 = lane & 15;
  const int wm = (wv >> 1) * 64;
  const int wn = (wv & 1) * 64;

  const f32x4 fz = {0.f, 0.f, 0.f, 0.f};
  f32x4 accG[4][4], accU[4][4];
#pragma unroll
  for (int i = 0; i < 4; ++i)
#pragma unroll
    for (int j = 0; j < 4; ++j) { accG[i][j] = fz; accU[i][j] = fz; }

  bf16x8 av[4];
  bf16x8 bv[8];
#pragma unroll
  for (int p = 0; p < 4; ++p) av[p] = *(const bf16x8*)(aSrc[p]);
#pragma unroll
  for (int p = 0; p < 8; ++p)
    bv[p] = *(const bf16x8*)(bSrc + (long)(p * 16) * DMODEL);

  for (int k0 = 0; k0 < DMODEL; k0 += 64) {
    LGKM_BAR();  // previous frag reads done (no vmcnt drain)
#pragma unroll
    for (int p = 0; p < 4; ++p)
      *(bf16x8*)(As + aoct * PLANE + (p * 32 + arw) * 16) = av[p];
#pragma unroll
    for (int p = 0; p < 8; ++p)
      *(bf16x8*)(bDst + boct * PLANE + (p * 16 + brw) * 16) = bv[p];
    const int kn = k0 + 64;
    if (kn < DMODEL) {
#pragma unroll
      for (int p = 0; p < 4; ++p) av[p] = *(const bf16x8*)(aSrc[p] + kn);
#pragma unroll
      for (int p = 0; p < 8; ++p)
        bv[p] = *(const bf16x8*)(bSrc + (long)(p * 16) * DMODEL + kn);
    }
    LGKM_BAR();  // ds_writes visible; prefetch stays in flight
#pragma unroll
    for (int kb = 0; kb < 2; ++kb) {
      bf16x8 aF[4];
#pragma unroll
      for (int mi = 0; mi < 4; ++mi)
        aF[mi] = *(const bf16x8*)(As + (4 * kb + q) * PLANE + (wm + 16 * mi + l15) * 16);
#pragma unroll
      for (int ni = 0; ni < 4; ++ni) {
        const int br = wn + 16 * ni + l15;
        const bf16x8 gF = *(const bf16x8*)(Bg + (4 * kb + q) * PLANE + br * 16);
        const bf16x8 uF = *(const bf16x8*)(Bu + (4 * kb + q) * PLANE + br * 16);
#pragma unroll
        for (int mi = 0; mi < 4; ++mi) {
          accG[mi][ni] = __builtin_amdgcn_mfma_f32_16x16x32_bf16(aF[mi], gF, accG[mi][ni], 0, 0, 0);
          accU[mi][ni] = __builtin_amdgcn_mfma_f32_16x16x32_bf16(aF[mi], uF, accU[mi][ni], 0, 0, 0);
        }
      }
    }
  }

  bf16* outI = shd ? interS : interR;
  const int ldI = shd ? NSHI : INTER;
#pragma unroll
  for (int mi = 0; mi < 4; ++mi)
#pragma unroll
    for (int r = 0; r < 4; ++r) {
      const int rowLoc = wm + 16 * mi + q * 4 + r;
      const int row = rowStart + rowLoc;
      if (row < rowEnd) {
#pragma unroll
        for (int ni = 0; ni < 4; ++ni) {
          const float gg = accG[mi][ni][r];
          const float uu = accU[mi][ni][r];
          const float sv = gg / (1.f + __expf(-gg)) * uu;
          outI[(long)row * ldI + (n0 + wn + 16 * ni + l15)] = (bf16)sv;
        }
      }
    }
}

// ---------------- down grouped GEMM (128M x 128N, BK=64), bf16 weights ----------------
__global__ __launch_bounds__(256, 2)
void down_gemm(const bf16* __restrict__ interR, const bf16* __restrict__ interS,
               const int* __restrict__ offs, const int* __restrict__ tileE,
               const int* __restrict__ tileR, const int* __restrict__ tileCnt,
               const bf16* __restrict__ wbf,
               float* __restrict__ dsR, float* __restrict__ dsS) {
  const int y = blockIdx.y;
  if (y >= tileCnt[0]) return;
  const int e = tileE[y];
  const bool shd = (e == NEXP);
  const int n0 = blockIdx.x * 128;
  const int rowStart = tileR[y];
  const int rowEnd = shd ? rowStart + 128 : offs[e + 1];
  const int Kd = shd ? NSHI : INTER;
  const bf16* A = shd ? interS : interR;
  const bf16* wd = shd ? wbf + OFF_SD : wbf + OFF_DP + (long)e * DMODEL * INTER;

  __shared__ __attribute__((aligned(16))) char As[8 * PLANE];
  __shared__ __attribute__((aligned(16))) char Bs[8 * PLANE];

  const int tid = threadIdx.x;
  // A staging (rows sequential; tail rows masked on store)
  const int arw = tid >> 3;
  const int aoct = tid & 7;
  const bf16* aSrc[4];
#pragma unroll
  for (int p = 0; p < 4; ++p)
    aSrc[p] = A + (long)(rowStart + p * 32 + arw) * Kd + aoct * 8;

  // B staging: 256 threads, 128 N-rows: round p: row = p*32 + (tid>>3), oct = tid&7
  const int brw = tid >> 3;  // 0..31
  const int boct = tid & 7;
  const bf16* bSrc = wd + (long)(n0 + brw) * Kd + boct * 8;

  const int lane = tid & 63;
  const int wv = tid >> 6;
  const int q = lane >> 4;
  const int l15 = lane & 15;
  const int wm = (wv >> 1) * 64;
  const int wn = (wv & 1) * 64;

  const f32x4 fz = {0.f, 0.f, 0.f, 0.f};
  f32x4 acc[4][4];
#pragma unroll
  for (int i = 0; i < 4; ++i)
#pragma unroll
    for (int j = 0; j < 4; ++j) acc[i][j] = fz;

  bf16x8 av[4];
  bf16x8 bv[4];
#pragma unroll
  for (int p = 0; p < 4; ++p) av[p] = *(const bf16x8*)(aSrc[p]);
#pragma unroll
  for (int p = 0; p < 4; ++p)
    bv[p] = *(const bf16x8*)(bSrc + (long)(p * 32) * Kd);

  for (int k0 = 0; k0 < Kd; k0 += 64) {
    LGKM_BAR();
#pragma unroll
    for (int p = 0; p < 4; ++p)
      *(bf16x8*)(As + aoct * PLANE + (p * 32 + arw) * 16) = av[p];
#pragma unroll
    for (int p = 0; p < 4; ++p)
      *(bf16x8*)(Bs + boct * PLANE + (p * 32 + brw) * 16) = bv[p];
    const int kn = k0 + 64;
    if (kn < Kd) {
#pragma unroll
      for (int p = 0; p < 4; ++p) av[p] = *(const bf16x8*)(aSrc[p] + kn);
#pragma unroll
      for (int p = 0; p < 4; ++p)
        bv[p] = *(const bf16x8*)(bSrc + (long)(p * 32) * Kd + kn);
    }
    LGKM_BAR();
#pragma unroll
    for (int kb = 0; kb < 2; ++kb) {
      bf16x8 aF[4];
#pragma unroll
      for (int mi = 0; mi < 4; ++mi)
        aF[mi] = *(const bf16x8*)(As + (4 * kb + q) * PLANE + (wm + 16 * mi + l15) * 16);
#pragma unroll
      for (int ni = 0; ni < 4; ++ni) {
        const bf16x8 bF = *(const bf16x8*)(Bs + (4 * kb + q) * PLANE + (wn + 16 * ni + l15) * 16);
#pragma unroll
        for (int mi = 0; mi < 4; ++mi)
          acc[mi][ni] = __builtin_amdgcn_mfma_f32_16x16x32_bf16(aF[mi], bF, acc[mi][ni], 0, 0, 0);
      }
    }
  }

  float* dst = shd ? dsS : dsR;
#pragma unroll
  for (int mi = 0; mi < 4; ++mi)
#pragma unroll
    for (int r = 0; r < 4; ++r) {
      const int rowLoc = wm + 16 * mi + q * 4 + r;
      const int row = rowStart + rowLoc;
      if (row < rowEnd) {
#pragma unroll
        for (int ni = 0; ni < 4; ++ni)
          dst[(long)row * DMODEL + (n0 + wn + 16 * ni + l15)] = acc[mi][ni][r];
      }
    }
}

// ---------------- combine: out[t] = shared[t] + sum_k w * routed[slot_k] ----------------
__global__ __launch_bounds__(256)
void combine_kernel(const float* __restrict__ dsR, const float* __restrict__ dsS,
                    const int* __restrict__ tokSlot, const float* __restrict__ tokW,
                    float* __restrict__ out) {
  const int t = blockIdx.x;
  const int j = threadIdx.x;  // float4 column
  float4 v = ((const float4*)(dsS + (long)t * DMODEL))[j];
#pragma unroll
  for (int k = 0; k < TOPK; ++k) {
    const int s = tokSlot[t * TOPK + k];
    const float w = tokW[t * TOPK + k];
    const float4 r = ((const float4*)(dsR + (long)s * DMODEL))[j];
    v.x += w * r.x; v.y += w * r.y; v.z += w * r.z; v.w += w * r.w;
  }
  ((float4*)(out + (long)t * DMODEL))[j] = v;
}

extern "C" void kernel_launch(void* const* d_in, const int* in_sizes, int n_in,
                              void* d_out, int out_size, void* d_ws, size_t ws_size,
                              hipStream_t stream) {
  const float* x  = (const float*)d_in[0];
  const float* gw = (const float*)d_in[2];
  const float* gb = (const float*)d_in[3];
  const float* gp = (const float*)d_in[4];
  const float* up = (const float*)d_in[5];
  const float* dp = (const float*)d_in[6];
  const float* sg = (const float*)d_in[7];
  const float* su = (const float*)d_in[8];
  const float* sd = (const float*)d_in[9];
  float* out = (float*)d_out;

  char* base = (char*)d_ws;
  size_t off = 0;
  auto alloc = [&](size_t bytes) -> char* {
    off = (off + 255) & ~(size_t)255;
    char* p = base + off;
    off += bytes;
    return p;
  };
  bf16* wbf = (bf16*)alloc((size_t)WTOT * 2);           // 56.6 MB bf16 weights
  bf16* xbf = (bf16*)alloc((size_t)TTOK * DMODEL * 2);
  bf16* interR = (bf16*)alloc((size_t)(TTOK * TOPK + 128) * INTER * 2);
  bf16* interS = (bf16*)alloc((size_t)TTOK * NSHI * 2);
  float* dsR = (float*)alloc((size_t)TTOK * TOPK * DMODEL * 4);
  float* dsS = (float*)alloc((size_t)TTOK * DMODEL * 4);
  float* scores = (float*)alloc((size_t)TTOK * NEXP * 4);
  float* tokW = (float*)alloc(TTOK * TOPK * 4);
  int* slotTok = (int*)alloc(TTOK * TOPK * 4);
  int* tokSlot = (int*)alloc(TTOK * TOPK * 4);
  int* offs = (int*)alloc((NEXP + 1) * 4);
  int* tileE = (int*)alloc(72 * 4);
  int* tileR = (int*)alloc(72 * 4);
  int* tileCnt = (int*)alloc(4);

  convert_kernel<<<6912, 256, 0, stream>>>(gp, up, dp, sg, su, sd, wbf);
  scores_kernel<<<TTOK / 4, 256, 0, stream>>>(x, gw, scores, xbf);
  route_kernel<<<1, 1024, 0, stream>>>(scores, gb, tokW, slotTok, tokSlot,
                                       offs, tileE, tileR, tileCnt);

  gateup_gemm<<<dim3(8, 56, 1), 256, 0, stream>>>(
      xbf, slotTok, offs, tileE, tileR, tileCnt, wbf, interR, interS);
  down_gemm<<<dim3(8, 56, 1), 256, 0, stream>>>(
      interR, interS, offs, tileE, tileR, tileCnt, wbf, dsR, dsS);
  combine_kernel<<<TTOK, 256, 0, stream>>>(dsR, dsS, tokSlot, tokW, out);
}

// Round 8
// 231.577 us; speedup vs baseline: 1.0072x; 1.0072x over previous
//
#include <hip/hip_runtime.h>
#include <stdint.h>

#define TTOK 1024
#define DMODEL 1024
#define NEXP 16
#define TOPK 4
#define INTER 512
#define NSHI 1024
#define RSCALE 2.5f

typedef __bf16 bf16;
typedef __bf16 bf16x8 __attribute__((ext_vector_type(8)));
typedef __bf16 bf16x4 __attribute__((ext_vector_type(4)));
typedef float f32x4 __attribute__((ext_vector_type(4)));

// LDS plane strides (+16B pad so write banks spread)
#define APLANE 2064  // 128 rows * 16B + 16
#define BPLANE 528   // 32 rows * 16B + 16

// Raw barrier: lgkmcnt(0) for cross-wave LDS safety, no vmcnt drain —
// prefetched global loads stay in flight across the barrier.
#define LGKM_BAR()                                            \
  do {                                                        \
    asm volatile("s_waitcnt lgkmcnt(0)" ::: "memory");        \
    __builtin_amdgcn_s_barrier();                             \
  } while (0)

// ---------------- scores (+ fused x->bf16): logits = x @ gw^T, fp32 exact ----------------
__global__ __launch_bounds__(256)
void scores_kernel(const float* __restrict__ x, const float* __restrict__ gw,
                   float* __restrict__ scores, bf16* __restrict__ xbf) {
  __shared__ float gws[16 * 1024];
  const int tid = threadIdx.x;
  const float4* gw4 = (const float4*)gw;
#pragma unroll
  for (int i0 = 0; i0 < 4096; i0 += 256) {
    const int i = i0 + tid;
    const int e = i >> 8;
    const int dq = (i & 255) << 2;
    const int dd = (dq + 4 * e) & 1023;
    ((float4*)gws)[(e << 8) + (dd >> 2)] = gw4[i];
  }
  // fused x -> bf16 (4 tokens/block, 1024 float4)
  {
    const long xb = (long)blockIdx.x * 1024;
#pragma unroll
    for (int p = 0; p < 4; ++p) {
      const long j = xb + p * 256 + tid;
      const float4 v = ((const float4*)x)[j];
      bf16x4 o;
      o.x = (bf16)v.x; o.y = (bf16)v.y; o.z = (bf16)v.z; o.w = (bf16)v.w;
      ((bf16x4*)xbf)[j] = o;
    }
  }
  __syncthreads();
  const int kq = tid >> 6;
  const int lane = tid & 63;
  const int tl = lane >> 4;
  const int e = lane & 15;
  const long token = (long)blockIdx.x * 4 + tl;
  float acc = 0.f;
  const int dbase = kq * 256;
#pragma unroll 8
  for (int i = 0; i < 256; i += 4) {
    const int d = dbase + i;
    const float4 xv = *(const float4*)&x[token * DMODEL + d];
    const float4 wv = *(const float4*)&gws[(e << 10) + ((d + 4 * e) & 1023)];
    acc += xv.x * wv.x + xv.y * wv.y + xv.z * wv.z + xv.w * wv.w;
  }
  __syncthreads();
  gws[kq * 64 + lane] = acc;
  __syncthreads();
  if (kq == 0) {
    const float s = gws[lane] + gws[64 + lane] + gws[128 + lane] + gws[192 + lane];
    scores[token * 16 + e] = s;
  }
}

// ---------------- route: top-k + plan + fill, fused single-block ----------------
__global__ __launch_bounds__(1024)
void route_kernel(const float* __restrict__ scores, const float* __restrict__ gb,
                  float* __restrict__ tokW, int* __restrict__ slotTok,
                  int* __restrict__ tokSlot, int* __restrict__ offs,
                  int* __restrict__ tileE, int* __restrict__ tileR,
                  int* __restrict__ tileCnt) {
  __shared__ int cnt[NEXP], cur[NEXP];
  const int t = threadIdx.x;
  if (t < NEXP) cnt[t] = 0;
  __syncthreads();
  float sc[NEXP], s[NEXP];
#pragma unroll
  for (int e = 0; e < NEXP; ++e) {
    const float l = scores[t * NEXP + e];
    sc[e] = 1.f / (1.f + expf(-l));
    s[e] = sc[e] + gb[e];
  }
  float gsc[4];
#pragma unroll
  for (int g = 0; g < 4; ++g) {
    const float a = s[4 * g], b = s[4 * g + 1], c = s[4 * g + 2], d = s[4 * g + 3];
    gsc[g] = fmaxf(fmaxf(fmaxf(a + b, a + c), fmaxf(a + d, b + c)),
                   fmaxf(b + d, c + d));
  }
  int g0 = 0;
  for (int g = 1; g < 4; ++g) if (gsc[g] > gsc[g0]) g0 = g;
  int g1 = (g0 == 0) ? 1 : 0;
  for (int g = 0; g < 4; ++g) if (g != g0 && gsc[g] > gsc[g1]) g1 = g;
  float m[NEXP];
#pragma unroll
  for (int e = 0; e < NEXP; ++e) {
    const int g = e >> 2;
    m[e] = (g == g0 || g == g1) ? s[e] : -1.f;
  }
  int idx[TOPK]; float wv[TOPK]; float wsum = 0.f;
  for (int k = 0; k < TOPK; ++k) {
    int am = 0; float best = m[0];
    for (int e2 = 1; e2 < NEXP; ++e2)
      if (m[e2] > best) { best = m[e2]; am = e2; }
    idx[k] = am; wv[k] = sc[am]; wsum += sc[am]; m[am] = -2.f;
  }
#pragma unroll
  for (int k = 0; k < TOPK; ++k) atomicAdd(&cnt[idx[k]], 1);
  __syncthreads();
  if (t == 0) {
    int acc = 0;
#pragma unroll
    for (int e = 0; e < NEXP; ++e) {
      offs[e] = acc; cur[e] = acc; acc += cnt[e];
    }
    offs[NEXP] = acc;
    int tc = 0;
    int roff = 0;
    for (int e = 0; e < NEXP; ++e) {
      const int end = roff + cnt[e];
      for (int r = roff; r < end; r += 128) { tileE[tc] = e; tileR[tc] = r; ++tc; }
      roff = end;
    }
    for (int r = 0; r < TTOK; r += 128) { tileE[tc] = NEXP; tileR[tc] = r; ++tc; }
    tileCnt[0] = tc;  // <= 47 + 8 = 55
  }
  __syncthreads();
  const float scl = RSCALE / wsum;
#pragma unroll
  for (int k = 0; k < TOPK; ++k) {
    const int slot = atomicAdd(&cur[idx[k]], 1);
    slotTok[slot] = t;
    tokSlot[t * TOPK + k] = slot;
    tokW[t * TOPK + k] = wv[k] * scl;
  }
}

// ---------------- gate+up grouped GEMM (128M x 32N, BK=64), fp32 weights, fused SwiGLU ----
// N=32 tiles: 2x the active blocks (~900) at UNCHANGED B-volume (x-blocks read
// disjoint N-slices) -> weight-stream rate scales with concurrency (round-1 data)
// without round-1's volume penalty. No separate convert pass.
__global__ __launch_bounds__(256, 2)
void gateup_gemm(const bf16* __restrict__ xbf, const int* __restrict__ slotTok,
                 const int* __restrict__ offs, const int* __restrict__ tileE,
                 const int* __restrict__ tileR, const int* __restrict__ tileCnt,
                 const float* __restrict__ Wg, const float* __restrict__ Wu,
                 const float* __restrict__ Sg, const float* __restrict__ Su,
                 bf16* __restrict__ interR, bf16* __restrict__ interS) {
  const int y = blockIdx.y;
  if (y >= tileCnt[0]) return;
  const int e = tileE[y];
  const bool shd = (e == NEXP);
  const int n0 = blockIdx.x * 32;
  if (!shd && n0 >= INTER) return;  // routed: x 0..15; shared: x 0..31
  const int rowStart = tileR[y];
  const int rowEnd = shd ? rowStart + 128 : offs[e + 1];
  const float* wgp = shd ? Sg : Wg + (long)e * INTER * DMODEL;
  const float* wup = shd ? Su : Wu + (long)e * INTER * DMODEL;

  __shared__ __attribute__((aligned(16))) char As[8 * APLANE];
  __shared__ __attribute__((aligned(16))) char Bg[8 * BPLANE];
  __shared__ __attribute__((aligned(16))) char Bu[8 * BPLANE];
  __shared__ int tokS[128];

  const int tid = threadIdx.x;
  if (tid < 128) {
    const int r = rowStart + tid;
    tokS[tid] = shd ? r : slotTok[r < rowEnd ? r : rowStart];
  }
  __syncthreads();

  // A staging: round p: row = p*32 + (tid>>3), oct = tid&7
  const int arw = tid >> 3;
  const int aoct = tid & 7;
  const bf16* aSrc[4];
#pragma unroll
  for (int p = 0; p < 4; ++p)
    aSrc[p] = xbf + (long)tokS[p * 32 + arw] * DMODEL + aoct * 8;

  // B staging (fp32): 128 threads per matrix; 32 rows x 16 float4:
  // round p: row = p*8 + (u>>4), f4 = u&15
  const int bu_ = tid >> 7;
  const int u = tid & 127;
  const int brw = u >> 4;   // 0..7
  const int bf4 = u & 15;
  const int boct = bf4 >> 1;
  const int bhalf = bf4 & 1;
  const float* bSrc = (bu_ ? wup : wgp) + (long)n0 * DMODEL + bf4 * 4;
  char* bDst = bu_ ? Bu : Bg;

  const int lane = tid & 63;
  const int wv = tid >> 6;
  const int q = lane >> 4;
  const int l15 = lane & 15;
  const int wm = wv * 32;  // each wave: 32 M-rows x full 32 N

  const f32x4 fz = {0.f, 0.f, 0.f, 0.f};
  f32x4 accG[2][2], accU[2][2];
#pragma unroll
  for (int i = 0; i < 2; ++i)
#pragma unroll
    for (int j = 0; j < 2; ++j) { accG[i][j] = fz; accU[i][j] = fz; }

  bf16x8 av[4];
  float4 bv[4];
#pragma unroll
  for (int p = 0; p < 4; ++p) av[p] = *(const bf16x8*)(aSrc[p]);
#pragma unroll
  for (int p = 0; p < 4; ++p)
    bv[p] = *(const float4*)(bSrc + (long)(p * 8 + brw) * DMODEL);

  for (int k0 = 0; k0 < DMODEL; k0 += 64) {
    LGKM_BAR();  // previous frag reads done (no vmcnt drain)
#pragma unroll
    for (int p = 0; p < 4; ++p)
      *(bf16x8*)(As + aoct * APLANE + (p * 32 + arw) * 16) = av[p];
#pragma unroll
    for (int p = 0; p < 4; ++p) {
      bf16x4 w;
      w.x = (bf16)bv[p].x; w.y = (bf16)bv[p].y; w.z = (bf16)bv[p].z; w.w = (bf16)bv[p].w;
      *(bf16x4*)(bDst + boct * BPLANE + (p * 8 + brw) * 16 + bhalf * 8) = w;
    }
    const int kn = k0 + 64;
    if (kn < DMODEL) {
#pragma unroll
      for (int p = 0; p < 4; ++p) av[p] = *(const bf16x8*)(aSrc[p] + kn);
#pragma unroll
      for (int p = 0; p < 4; ++p)
        bv[p] = *(const float4*)(bSrc + (long)(p * 8 + brw) * DMODEL + kn);
    }
    LGKM_BAR();  // ds_writes visible; prefetch stays in flight
#pragma unroll
    for (int kb = 0; kb < 2; ++kb) {
      bf16x8 aF[2];
#pragma unroll
      for (int mi = 0; mi < 2; ++mi)
        aF[mi] = *(const bf16x8*)(As + (4 * kb + q) * APLANE + (wm + 16 * mi + l15) * 16);
#pragma unroll
      for (int ni = 0; ni < 2; ++ni) {
        const int br = 16 * ni + l15;
        const bf16x8 gF = *(const bf16x8*)(Bg + (4 * kb + q) * BPLANE + br * 16);
        const bf16x8 uF = *(const bf16x8*)(Bu + (4 * kb + q) * BPLANE + br * 16);
#pragma unroll
        for (int mi = 0; mi < 2; ++mi) {
          accG[mi][ni] = __builtin_amdgcn_mfma_f32_16x16x32_bf16(aF[mi], gF, accG[mi][ni], 0, 0, 0);
          accU[mi][ni] = __builtin_amdgcn_mfma_f32_16x16x32_bf16(aF[mi], uF, accU[mi][ni], 0, 0, 0);
        }
      }
    }
  }

  bf16* outI = shd ? interS : interR;
  const int ldI = shd ? NSHI : INTER;
#pragma unroll
  for (int mi = 0; mi < 2; ++mi)
#pragma unroll
    for (int r = 0; r < 4; ++r) {
      const int rowLoc = wm + 16 * mi + q * 4 + r;
      const int row = rowStart + rowLoc;
      if (row < rowEnd) {
#pragma unroll
        for (int ni = 0; ni < 2; ++ni) {
          const float gg = accG[mi][ni][r];
          const float uu = accU[mi][ni][r];
          const float sv = gg / (1.f + __expf(-gg)) * uu;
          outI[(long)row * ldI + (n0 + 16 * ni + l15)] = (bf16)sv;
        }
      }
    }
}

// ---------------- down grouped GEMM (128M x 32N, BK=64), fp32 weights ----------------
__global__ __launch_bounds__(256, 2)
void down_gemm(const bf16* __restrict__ interR, const bf16* __restrict__ interS,
               const int* __restrict__ offs, const int* __restrict__ tileE,
               const int* __restrict__ tileR, const int* __restrict__ tileCnt,
               const float* __restrict__ Wd, const float* __restrict__ Sd,
               float* __restrict__ dsR, float* __restrict__ dsS) {
  const int y = blockIdx.y;
  if (y >= tileCnt[0]) return;
  const int e = tileE[y];
  const bool shd = (e == NEXP);
  const int n0 = blockIdx.x * 32;  // 0..992, all active
  const int rowStart = tileR[y];
  const int rowEnd = shd ? rowStart + 128 : offs[e + 1];
  const int Kd = shd ? NSHI : INTER;
  const bf16* A = shd ? interS : interR;
  const float* wd = shd ? Sd : Wd + (long)e * DMODEL * INTER;

  __shared__ __attribute__((aligned(16))) char As[8 * APLANE];
  __shared__ __attribute__((aligned(16))) char Bs[8 * BPLANE];

  const int tid = threadIdx.x;
  // A staging (rows sequential; tail rows masked on store)
  const int arw = tid >> 3;
  const int aoct = tid & 7;
  const bf16* aSrc[4];
#pragma unroll
  for (int p = 0; p < 4; ++p)
    aSrc[p] = A + (long)(rowStart + p * 32 + arw) * Kd + aoct * 8;

  // B staging (fp32): 256 threads; 32 rows x 16 float4:
  // round p: row = p*16 + (tid>>4), f4 = tid&15
  const int brw = tid >> 4;  // 0..15
  const int bf4 = tid & 15;
  const int boct = bf4 >> 1;
  const int bhalf = bf4 & 1;
  const float* bSrc = wd + (long)n0 * Kd + bf4 * 4;

  const int lane = tid & 63;
  const int wv = tid >> 6;
  const int q = lane >> 4;
  const int l15 = lane & 15;
  const int wm = wv * 32;

  const f32x4 fz = {0.f, 0.f, 0.f, 0.f};
  f32x4 acc[2][2];
#pragma unroll
  for (int i = 0; i < 2; ++i)
#pragma unroll
    for (int j = 0; j < 2; ++j) acc[i][j] = fz;

  bf16x8 av[4];
  float4 bv[2];
#pragma unroll
  for (int p = 0; p < 4; ++p) av[p] = *(const bf16x8*)(aSrc[p]);
#pragma unroll
  for (int p = 0; p < 2; ++p)
    bv[p] = *(const float4*)(bSrc + (long)(p * 16 + brw) * Kd);

  for (int k0 = 0; k0 < Kd; k0 += 64) {
    LGKM_BAR();
#pragma unroll
    for (int p = 0; p < 4; ++p)
      *(bf16x8*)(As + aoct * APLANE + (p * 32 + arw) * 16) = av[p];
#pragma unroll
    for (int p = 0; p < 2; ++p) {
      bf16x4 w;
      w.x = (bf16)bv[p].x; w.y = (bf16)bv[p].y; w.z = (bf16)bv[p].z; w.w = (bf16)bv[p].w;
      *(bf16x4*)(Bs + boct * BPLANE + (p * 16 + brw) * 16 + bhalf * 8) = w;
    }
    const int kn = k0 + 64;
    if (kn < Kd) {
#pragma unroll
      for (int p = 0; p < 4; ++p) av[p] = *(const bf16x8*)(aSrc[p] + kn);
#pragma unroll
      for (int p = 0; p < 2; ++p)
        bv[p] = *(const float4*)(bSrc + (long)(p * 16 + brw) * Kd + kn);
    }
    LGKM_BAR();
#pragma unroll
    for (int kb = 0; kb < 2; ++kb) {
      bf16x8 aF[2];
#pragma unroll
      for (int mi = 0; mi < 2; ++mi)
        aF[mi] = *(const bf16x8*)(As + (4 * kb + q) * APLANE + (wm + 16 * mi + l15) * 16);
#pragma unroll
      for (int ni = 0; ni < 2; ++ni) {
        const bf16x8 bF = *(const bf16x8*)(Bs + (4 * kb + q) * BPLANE + (16 * ni + l15) * 16);
#pragma unroll
        for (int mi = 0; mi < 2; ++mi)
          acc[mi][ni] = __builtin_amdgcn_mfma_f32_16x16x32_bf16(aF[mi], bF, acc[mi][ni], 0, 0, 0);
      }
    }
  }

  float* dst = shd ? dsS : dsR;
#pragma unroll
  for (int mi = 0; mi < 2; ++mi)
#pragma unroll
    for (int r = 0; r < 4; ++r) {
      const int rowLoc = wm + 16 * mi + q * 4 + r;
      const int row = rowStart + rowLoc;
      if (row < rowEnd) {
#pragma unroll
        for (int ni = 0; ni < 2; ++ni)
          dst[(long)row * DMODEL + (n0 + 16 * ni + l15)] = acc[mi][ni][r];
      }
    }
}

// ---------------- combine: out[t] = shared[t] + sum_k w * routed[slot_k] ----------------
__global__ __launch_bounds__(256)
void combine_kernel(const float* __restrict__ dsR, const float* __restrict__ dsS,
                    const int* __restrict__ tokSlot, const float* __restrict__ tokW,
                    float* __restrict__ out) {
  const int t = blockIdx.x;
  const int j = threadIdx.x;  // float4 column
  float4 v = ((const float4*)(dsS + (long)t * DMODEL))[j];
#pragma unroll
  for (int k = 0; k < TOPK; ++k) {
    const int s = tokSlot[t * TOPK + k];
    const float w = tokW[t * TOPK + k];
    const float4 r = ((const float4*)(dsR + (long)s * DMODEL))[j];
    v.x += w * r.x; v.y += w * r.y; v.z += w * r.z; v.w += w * r.w;
  }
  ((float4*)(out + (long)t * DMODEL))[j] = v;
}

extern "C" void kernel_launch(void* const* d_in, const int* in_sizes, int n_in,
                              void* d_out, int out_size, void* d_ws, size_t ws_size,
                              hipStream_t stream) {
  const float* x  = (const float*)d_in[0];
  const float* gw = (const float*)d_in[2];
  const float* gb = (const float*)d_in[3];
  const float* gp = (const float*)d_in[4];
  const float* up = (const float*)d_in[5];
  const float* dp = (const float*)d_in[6];
  const float* sg = (const float*)d_in[7];
  const float* su = (const float*)d_in[8];
  const float* sd = (const float*)d_in[9];
  float* out = (float*)d_out;

  char* base = (char*)d_ws;
  size_t off = 0;
  auto alloc = [&](size_t bytes) -> char* {
    off = (off + 255) & ~(size_t)255;
    char* p = base + off;
    off += bytes;
    return p;
  };
  bf16* xbf = (bf16*)alloc((size_t)TTOK * DMODEL * 2);
  bf16* interR = (bf16*)alloc((size_t)(TTOK * TOPK + 128) * INTER * 2);
  bf16* interS = (bf16*)alloc((size_t)TTOK * NSHI * 2);
  float* dsR = (float*)alloc((size_t)TTOK * TOPK * DMODEL * 4);
  float* dsS = (float*)alloc((size_t)TTOK * DMODEL * 4);
  float* scores = (float*)alloc((size_t)TTOK * NEXP * 4);
  float* tokW = (float*)alloc(TTOK * TOPK * 4);
  int* slotTok = (int*)alloc(TTOK * TOPK * 4);
  int* tokSlot = (int*)alloc(TTOK * TOPK * 4);
  int* offs = (int*)alloc((NEXP + 1) * 4);
  int* tileE = (int*)alloc(72 * 4);
  int* tileR = (int*)alloc(72 * 4);
  int* tileCnt = (int*)alloc(4);

  scores_kernel<<<TTOK / 4, 256, 0, stream>>>(x, gw, scores, xbf);
  route_kernel<<<1, 1024, 0, stream>>>(scores, gb, tokW, slotTok, tokSlot,
                                       offs, tileE, tileR, tileCnt);

  gateup_gemm<<<dim3(32, 56, 1), 256, 0, stream>>>(
      xbf, slotTok, offs, tileE, tileR, tileCnt, gp, up, sg, su, interR, interS);
  down_gemm<<<dim3(32, 56, 1), 256, 0, stream>>>(
      interR, interS, offs, tileE, tileR, tileCnt, dp, sd, dsR, dsS);
  combine_kernel<<<TTOK, 256, 0, stream>>>(dsR, dsS, tokSlot, tokW, out);
}

// Round 9
// 219.949 us; speedup vs baseline: 1.0604x; 1.0529x over previous
//
#include <hip/hip_runtime.h>
#include <stdint.h>

#define TTOK 1024
#define DMODEL 1024
#define NEXP 16
#define TOPK 4
#define INTER 512
#define NSHI 1024
#define RSCALE 2.5f

typedef __bf16 bf16;
typedef __bf16 bf16x8 __attribute__((ext_vector_type(8)));
typedef __bf16 bf16x4 __attribute__((ext_vector_type(4)));
typedef float f32x4 __attribute__((ext_vector_type(4)));

// LDS oct-plane strides, padded +16B so write banks spread
#define APLANE 2064  // 128 rows * 16B + 16
#define BPLANE 1040  // 64 rows * 16B + 16

// bf16 weight buffer layout (element offsets)
#define OFF_GP 0L
#define OFF_UP 8388608L   // 16*512*1024
#define OFF_DP 16777216L
#define OFF_SG 25165824L
#define OFF_SU 26214400L
#define OFF_SD 27262976L
#define WTOT   28311552L  // total bf16 elems

#define SCORES_BLOCKS 256
#define CONV_BLOCKS 27648  // WTOT/4 float4 units / 256 threads

// Raw barrier: lgkmcnt(0) for cross-wave LDS safety, no vmcnt drain —
// prefetched global loads stay in flight across the barrier.
#define LGKM_BAR()                                            \
  do {                                                        \
    asm volatile("s_waitcnt lgkmcnt(0)" ::: "memory");        \
    __builtin_amdgcn_s_barrier();                             \
  } while (0)

// ---------------- prep: scores (+x->bf16) CONCURRENT with weight fp32->bf16 ----------------
// Blocks [0,256): scores for 4 tokens each, gw read from L2 (64 KB, hot), 1 KB LDS.
// Blocks [256, 256+27648): weight conversion (1 float4 -> bf16x4 per thread —
// the fastest measured convert variant). Convert overlaps scores/route latency.
__global__ __launch_bounds__(256)
void prep_kernel(const float* __restrict__ x, const float* __restrict__ gw,
                 float* __restrict__ scores, bf16* __restrict__ xbf,
                 const float* __restrict__ s0, const float* __restrict__ s1,
                 const float* __restrict__ s2, const float* __restrict__ s3,
                 const float* __restrict__ s4, const float* __restrict__ s5,
                 bf16* __restrict__ dst) {
  __shared__ float red[256];  // 1 KB only — convert blocks keep full occupancy
  const int b = blockIdx.x;
  const int tid = threadIdx.x;
  if (b < SCORES_BLOCKS) {
    // fused x -> bf16 (4 tokens/block, 1024 float4)
    const long xb = (long)b * 1024;
#pragma unroll
    for (int p = 0; p < 4; ++p) {
      const long j = xb + p * 256 + tid;
      const float4 v = ((const float4*)x)[j];
      bf16x4 o;
      o.x = (bf16)v.x; o.y = (bf16)v.y; o.z = (bf16)v.z; o.w = (bf16)v.w;
      ((bf16x4*)xbf)[j] = o;
    }
    // logits: thread (kq, token tl, expert e); gw from global (L2-hot)
    const int kq = tid >> 6;
    const int lane = tid & 63;
    const int tl = lane >> 4;
    const int e = lane & 15;
    const long token = (long)b * 4 + tl;
    float acc = 0.f;
    const int dbase = kq * 256;
#pragma unroll 8
    for (int i = 0; i < 256; i += 4) {
      const int d = dbase + i;
      const float4 xv = *(const float4*)&x[token * DMODEL + d];
      const float4 wv = *(const float4*)&gw[e * DMODEL + d];
      acc += xv.x * wv.x + xv.y * wv.y + xv.z * wv.z + xv.w * wv.w;
    }
    red[tid] = acc;
    __syncthreads();
    if (kq == 0) {
      const float s = red[lane] + red[64 + lane] + red[128 + lane] + red[192 + lane];
      scores[token * 16 + e] = s;
    }
  } else {
    const long i = (long)(b - SCORES_BLOCKS) * 256 + tid;  // float4 index
    const float* src;
    long local;
    if (i < 2097152)      { src = s0; local = i; }
    else if (i < 4194304) { src = s1; local = i - 2097152; }
    else if (i < 6291456) { src = s2; local = i - 4194304; }
    else if (i < 6553600) { src = s3; local = i - 6291456; }
    else if (i < 6815744) { src = s4; local = i - 6553600; }
    else                  { src = s5; local = i - 6815744; }
    const float4 v = ((const float4*)src)[local];
    bf16x4 o;
    o.x = (bf16)v.x; o.y = (bf16)v.y; o.z = (bf16)v.z; o.w = (bf16)v.w;
    ((bf16x4*)dst)[i] = o;
  }
}

// ---------------- route: top-k + plan + fill, fused single-block ----------------
__global__ __launch_bounds__(1024)
void route_kernel(const float* __restrict__ scores, const float* __restrict__ gb,
                  float* __restrict__ tokW, int* __restrict__ slotTok,
                  int* __restrict__ tokSlot, int* __restrict__ offs,
                  int* __restrict__ tileE, int* __restrict__ tileR,
                  int* __restrict__ tileCnt) {
  __shared__ int cnt[NEXP], cur[NEXP];
  const int t = threadIdx.x;
  if (t < NEXP) cnt[t] = 0;
  __syncthreads();
  float sc[NEXP], s[NEXP];
#pragma unroll
  for (int e = 0; e < NEXP; ++e) {
    const float l = scores[t * NEXP + e];
    sc[e] = 1.f / (1.f + expf(-l));
    s[e] = sc[e] + gb[e];
  }
  float gsc[4];
#pragma unroll
  for (int g = 0; g < 4; ++g) {
    const float a = s[4 * g], b = s[4 * g + 1], c = s[4 * g + 2], d = s[4 * g + 3];
    gsc[g] = fmaxf(fmaxf(fmaxf(a + b, a + c), fmaxf(a + d, b + c)),
                   fmaxf(b + d, c + d));
  }
  int g0 = 0;
  for (int g = 1; g < 4; ++g) if (gsc[g] > gsc[g0]) g0 = g;
  int g1 = (g0 == 0) ? 1 : 0;
  for (int g = 0; g < 4; ++g) if (g != g0 && gsc[g] > gsc[g1]) g1 = g;
  float m[NEXP];
#pragma unroll
  for (int e = 0; e < NEXP; ++e) {
    const int g = e >> 2;
    m[e] = (g == g0 || g == g1) ? s[e] : -1.f;
  }
  int idx[TOPK]; float wv[TOPK]; float wsum = 0.f;
  for (int k = 0; k < TOPK; ++k) {
    int am = 0; float best = m[0];
    for (int e2 = 1; e2 < NEXP; ++e2)
      if (m[e2] > best) { best = m[e2]; am = e2; }
    idx[k] = am; wv[k] = sc[am]; wsum += sc[am]; m[am] = -2.f;
  }
#pragma unroll
  for (int k = 0; k < TOPK; ++k) atomicAdd(&cnt[idx[k]], 1);
  __syncthreads();
  if (t == 0) {
    int acc = 0;
#pragma unroll
    for (int e = 0; e < NEXP; ++e) {
      offs[e] = acc; cur[e] = acc; acc += cnt[e];
    }
    offs[NEXP] = acc;
    int tc = 0;
    int roff = 0;
    for (int e = 0; e < NEXP; ++e) {
      const int end = roff + cnt[e];
      for (int r = roff; r < end; r += 128) { tileE[tc] = e; tileR[tc] = r; ++tc; }
      roff = end;
    }
    for (int r = 0; r < TTOK; r += 128) { tileE[tc] = NEXP; tileR[tc] = r; ++tc; }
    tileCnt[0] = tc;  // <= 47 + 8 = 55
  }
  __syncthreads();
  const float scl = RSCALE / wsum;
#pragma unroll
  for (int k = 0; k < TOPK; ++k) {
    const int slot = atomicAdd(&cur[idx[k]], 1);
    slotTok[slot] = t;
    tokSlot[t * TOPK + k] = slot;
    tokW[t * TOPK + k] = wv[k] * scl;
  }
}

// ---------------- gate+up grouped GEMM (128M x 64N, BK=64), bf16 weights, fused SwiGLU ----------------
__global__ __launch_bounds__(256, 2)
void gateup_gemm(const bf16* __restrict__ xbf, const int* __restrict__ slotTok,
                 const int* __restrict__ offs, const int* __restrict__ tileE,
                 const int* __restrict__ tileR, const int* __restrict__ tileCnt,
                 const bf16* __restrict__ wbf,
                 bf16* __restrict__ interR, bf16* __restrict__ interS) {
  const int y = blockIdx.y;
  if (y >= tileCnt[0]) return;
  const int e = tileE[y];
  const bool shd = (e == NEXP);
  const int n0 = blockIdx.x * 64;
  if (!shd && n0 >= INTER) return;
  const int rowStart = tileR[y];
  const int rowEnd = shd ? rowStart + 128 : offs[e + 1];
  const bf16* wgp = shd ? wbf + OFF_SG : wbf + OFF_GP + (long)e * INTER * DMODEL;
  const bf16* wup = shd ? wbf + OFF_SU : wbf + OFF_UP + (long)e * INTER * DMODEL;

  __shared__ __attribute__((aligned(16))) char As[8 * APLANE];
  __shared__ __attribute__((aligned(16))) char Bg[8 * BPLANE];
  __shared__ __attribute__((aligned(16))) char Bu[8 * BPLANE];
  __shared__ int tokS[128];

  const int tid = threadIdx.x;
  if (tid < 128) {
    const int r = rowStart + tid;
    tokS[tid] = shd ? r : slotTok[r < rowEnd ? r : rowStart];
  }
  __syncthreads();

  // A staging: round p: row = p*32 + (tid>>3), oct = tid&7
  const int arw = tid >> 3;
  const int aoct = tid & 7;
  const bf16* aSrc[4];
#pragma unroll
  for (int p = 0; p < 4; ++p)
    aSrc[p] = xbf + (long)tokS[p * 32 + arw] * DMODEL + aoct * 8;

  // B staging (bf16): 128 threads per matrix; round p: row = p*16 + (u>>3), oct = u&7
  const int bu_ = tid >> 7;
  const int u = tid & 127;
  const int brw = u >> 3;   // 0..15
  const int boct = u & 7;
  const bf16* bSrc = (bu_ ? wup : wgp) + (long)(n0 + brw) * DMODEL + boct * 8;
  char* bDst = bu_ ? Bu : Bg;

  const int lane = tid & 63;
  const int wv = tid >> 6;
  const int q = lane >> 4;
  const int l15 = lane & 15;
  const int wm = (wv >> 1) * 64;
  const int wn = (wv & 1) * 32;

  const f32x4 fz = {0.f, 0.f, 0.f, 0.f};
  f32x4 accG[4][2], accU[4][2];
#pragma unroll
  for (int i = 0; i < 4; ++i)
#pragma unroll
    for (int j = 0; j < 2; ++j) { accG[i][j] = fz; accU[i][j] = fz; }

  bf16x8 av[4];
  bf16x8 bv[4];
#pragma unroll
  for (int p = 0; p < 4; ++p) av[p] = *(const bf16x8*)(aSrc[p]);
#pragma unroll
  for (int p = 0; p < 4; ++p)
    bv[p] = *(const bf16x8*)(bSrc + (long)(p * 16) * DMODEL);

  for (int k0 = 0; k0 < DMODEL; k0 += 64) {
    LGKM_BAR();  // previous frag reads done (no vmcnt drain)
#pragma unroll
    for (int p = 0; p < 4; ++p)
      *(bf16x8*)(As + aoct * APLANE + (p * 32 + arw) * 16) = av[p];
#pragma unroll
    for (int p = 0; p < 4; ++p)
      *(bf16x8*)(bDst + boct * BPLANE + (p * 16 + brw) * 16) = bv[p];
    const int kn = k0 + 64;
    if (kn < DMODEL) {
#pragma unroll
      for (int p = 0; p < 4; ++p) av[p] = *(const bf16x8*)(aSrc[p] + kn);
#pragma unroll
      for (int p = 0; p < 4; ++p)
        bv[p] = *(const bf16x8*)(bSrc + (long)(p * 16) * DMODEL + kn);
    }
    LGKM_BAR();  // ds_writes visible; prefetch stays in flight
#pragma unroll
    for (int kb = 0; kb < 2; ++kb) {
      bf16x8 aF[4];
#pragma unroll
      for (int mi = 0; mi < 4; ++mi)
        aF[mi] = *(const bf16x8*)(As + (4 * kb + q) * APLANE + (wm + 16 * mi + l15) * 16);
#pragma unroll
      for (int ni = 0; ni < 2; ++ni) {
        const int br = wn + 16 * ni + l15;
        const bf16x8 gF = *(const bf16x8*)(Bg + (4 * kb + q) * BPLANE + br * 16);
        const bf16x8 uF = *(const bf16x8*)(Bu + (4 * kb + q) * BPLANE + br * 16);
#pragma unroll
        for (int mi = 0; mi < 4; ++mi) {
          accG[mi][ni] = __builtin_amdgcn_mfma_f32_16x16x32_bf16(aF[mi], gF, accG[mi][ni], 0, 0, 0);
          accU[mi][ni] = __builtin_amdgcn_mfma_f32_16x16x32_bf16(aF[mi], uF, accU[mi][ni], 0, 0, 0);
        }
      }
    }
  }

  bf16* outI = shd ? interS : interR;
  const int ldI = shd ? NSHI : INTER;
#pragma unroll
  for (int mi = 0; mi < 4; ++mi)
#pragma unroll
    for (int r = 0; r < 4; ++r) {
      const int rowLoc = wm + 16 * mi + q * 4 + r;
      const int row = rowStart + rowLoc;
      if (row < rowEnd) {
#pragma unroll
        for (int ni = 0; ni < 2; ++ni) {
          const float gg = accG[mi][ni][r];
          const float uu = accU[mi][ni][r];
          const float sv = gg / (1.f + __expf(-gg)) * uu;
          outI[(long)row * ldI + (n0 + wn + 16 * ni + l15)] = (bf16)sv;
        }
      }
    }
}

// ---------------- down grouped GEMM (128M x 64N, BK=64), bf16 weights ----------------
__global__ __launch_bounds__(256, 2)
void down_gemm(const bf16* __restrict__ interR, const bf16* __restrict__ interS,
               const int* __restrict__ offs, const int* __restrict__ tileE,
               const int* __restrict__ tileR, const int* __restrict__ tileCnt,
               const bf16* __restrict__ wbf,
               float* __restrict__ dsR, float* __restrict__ dsS) {
  const int y = blockIdx.y;
  if (y >= tileCnt[0]) return;
  const int e = tileE[y];
  const bool shd = (e == NEXP);
  const int n0 = blockIdx.x * 64;
  const int rowStart = tileR[y];
  const int rowEnd = shd ? rowStart + 128 : offs[e + 1];
  const int Kd = shd ? NSHI : INTER;
  const bf16* A = shd ? interS : interR;
  const bf16* wd = shd ? wbf + OFF_SD : wbf + OFF_DP + (long)e * DMODEL * INTER;

  __shared__ __attribute__((aligned(16))) char As[8 * APLANE];
  __shared__ __attribute__((aligned(16))) char Bs[8 * BPLANE];

  const int tid = threadIdx.x;
  // A staging (rows sequential; tail rows masked on store)
  const int arw = tid >> 3;
  const int aoct = tid & 7;
  const bf16* aSrc[4];
#pragma unroll
  for (int p = 0; p < 4; ++p)
    aSrc[p] = A + (long)(rowStart + p * 32 + arw) * Kd + aoct * 8;

  // B staging (bf16): 256 threads, 64 rows x 128B: round p: row = p*32 + (tid>>3), oct = tid&7
  const int brw = tid >> 3;  // 0..31
  const int boct = tid & 7;
  const bf16* bSrc = wd + (long)(n0 + brw) * Kd + boct * 8;

  const int lane = tid & 63;
  const int wv = tid >> 6;
  const int q = lane >> 4;
  const int l15 = lane & 15;
  const int wm = (wv >> 1) * 64;
  const int wn = (wv & 1) * 32;

  const f32x4 fz = {0.f, 0.f, 0.f, 0.f};
  f32x4 acc[4][2];
#pragma unroll
  for (int i = 0; i < 4; ++i)
#pragma unroll
    for (int j = 0; j < 2; ++j) acc[i][j] = fz;

  bf16x8 av[4];
  bf16x8 bv[2];
#pragma unroll
  for (int p = 0; p < 4; ++p) av[p] = *(const bf16x8*)(aSrc[p]);
#pragma unroll
  for (int p = 0; p < 2; ++p)
    bv[p] = *(const bf16x8*)(bSrc + (long)(p * 32) * Kd);

  for (int k0 = 0; k0 < Kd; k0 += 64) {
    LGKM_BAR();
#pragma unroll
    for (int p = 0; p < 4; ++p)
      *(bf16x8*)(As + aoct * APLANE + (p * 32 + arw) * 16) = av[p];
#pragma unroll
    for (int p = 0; p < 2; ++p)
      *(bf16x8*)(Bs + boct * BPLANE + (p * 32 + brw) * 16) = bv[p];
    const int kn = k0 + 64;
    if (kn < Kd) {
#pragma unroll
      for (int p = 0; p < 4; ++p) av[p] = *(const bf16x8*)(aSrc[p] + kn);
#pragma unroll
      for (int p = 0; p < 2; ++p)
        bv[p] = *(const bf16x8*)(bSrc + (long)(p * 32) * Kd + kn);
    }
    LGKM_BAR();
#pragma unroll
    for (int kb = 0; kb < 2; ++kb) {
      bf16x8 aF[4];
#pragma unroll
      for (int mi = 0; mi < 4; ++mi)
        aF[mi] = *(const bf16x8*)(As + (4 * kb + q) * APLANE + (wm + 16 * mi + l15) * 16);
#pragma unroll
      for (int ni = 0; ni < 2; ++ni) {
        const bf16x8 bF = *(const bf16x8*)(Bs + (4 * kb + q) * BPLANE + (wn + 16 * ni + l15) * 16);
#pragma unroll
        for (int mi = 0; mi < 4; ++mi)
          acc[mi][ni] = __builtin_amdgcn_mfma_f32_16x16x32_bf16(aF[mi], bF, acc[mi][ni], 0, 0, 0);
      }
    }
  }

  float* dst = shd ? dsS : dsR;
#pragma unroll
  for (int mi = 0; mi < 4; ++mi)
#pragma unroll
    for (int r = 0; r < 4; ++r) {
      const int rowLoc = wm + 16 * mi + q * 4 + r;
      const int row = rowStart + rowLoc;
      if (row < rowEnd) {
#pragma unroll
        for (int ni = 0; ni < 2; ++ni)
          dst[(long)row * DMODEL + (n0 + wn + 16 * ni + l15)] = acc[mi][ni][r];
      }
    }
}

// ---------------- combine: out[t] = shared[t] + sum_k w * routed[slot_k] ----------------
__global__ __launch_bounds__(256)
void combine_kernel(const float* __restrict__ dsR, const float* __restrict__ dsS,
                    const int* __restrict__ tokSlot, const float* __restrict__ tokW,
                    float* __restrict__ out) {
  const int t = blockIdx.x;
  const int j = threadIdx.x;  // float4 column
  float4 v = ((const float4*)(dsS + (long)t * DMODEL))[j];
#pragma unroll
  for (int k = 0; k < TOPK; ++k) {
    const int s = tokSlot[t * TOPK + k];
    const float w = tokW[t * TOPK + k];
    const float4 r = ((const float4*)(dsR + (long)s * DMODEL))[j];
    v.x += w * r.x; v.y += w * r.y; v.z += w * r.z; v.w += w * r.w;
  }
  ((float4*)(out + (long)t * DMODEL))[j] = v;
}

extern "C" void kernel_launch(void* const* d_in, const int* in_sizes, int n_in,
                              void* d_out, int out_size, void* d_ws, size_t ws_size,
                              hipStream_t stream) {
  const float* x  = (const float*)d_in[0];
  const float* gw = (const float*)d_in[2];
  const float* gb = (const float*)d_in[3];
  const float* gp = (const float*)d_in[4];
  const float* up = (const float*)d_in[5];
  const float* dp = (const float*)d_in[6];
  const float* sg = (const float*)d_in[7];
  const float* su = (const float*)d_in[8];
  const float* sd = (const float*)d_in[9];
  float* out = (float*)d_out;

  char* base = (char*)d_ws;
  size_t off = 0;
  auto alloc = [&](size_t bytes) -> char* {
    off = (off + 255) & ~(size_t)255;
    char* p = base + off;
    off += bytes;
    return p;
  };
  bf16* wbf = (bf16*)alloc((size_t)WTOT * 2);           // 56.6 MB bf16 weights
  bf16* xbf = (bf16*)alloc((size_t)TTOK * DMODEL * 2);
  bf16* interR = (bf16*)alloc((size_t)(TTOK * TOPK + 128) * INTER * 2);
  bf16* interS = (bf16*)alloc((size_t)TTOK * NSHI * 2);
  float* dsR = (float*)alloc((size_t)TTOK * TOPK * DMODEL * 4);
  float* dsS = (float*)alloc((size_t)TTOK * DMODEL * 4);
  float* scores = (float*)alloc((size_t)TTOK * NEXP * 4);
  float* tokW = (float*)alloc(TTOK * TOPK * 4);
  int* slotTok = (int*)alloc(TTOK * TOPK * 4);
  int* tokSlot = (int*)alloc(TTOK * TOPK * 4);
  int* offs = (int*)alloc((NEXP + 1) * 4);
  int* tileE = (int*)alloc(72 * 4);
  int* tileR = (int*)alloc(72 * 4);
  int* tileCnt = (int*)alloc(4);

  prep_kernel<<<SCORES_BLOCKS + CONV_BLOCKS, 256, 0, stream>>>(
      x, gw, scores, xbf, gp, up, dp, sg, su, sd, wbf);
  route_kernel<<<1, 1024, 0, stream>>>(scores, gb, tokW, slotTok, tokSlot,
                                       offs, tileE, tileR, tileCnt);

  gateup_gemm<<<dim3(16, 56, 1), 256, 0, stream>>>(
      xbf, slotTok, offs, tileE, tileR, tileCnt, wbf, interR, interS);
  down_gemm<<<dim3(16, 56, 1), 256, 0, stream>>>(
      interR, interS, offs, tileE, tileR, tileCnt, wbf, dsR, dsS);
  combine_kernel<<<TTOK, 256, 0, stream>>>(dsR, dsS, tokSlot, tokW, out);
}